// Round 3
// baseline (4248.292 us; speedup 1.0000x reference)
//
#include <hip/hip_runtime.h>
#include <stdint.h>

#define N_NEUR 4096
#define N_IN   512
#define BATCH  8
#define TSTEPS 1000
#define KB_REC 128                 // 128 k-blocks of 32 for recurrent W
#define KB_TOT 144                 // + 16 k-blocks for feedforward (K = 4608)
#define KB_PW  18                  // k-blocks per wave (144 / 8 waves)
#define STRIDE_OUT (BATCH * TSTEPS * N_NEUR)

// Spike-exchange layout: NCOPY replicas (readers per line = 256/NCOPY) and a
// 4352-byte (17*256) stride between 64B lines so the hot set spreads across
// ~all LLC channels instead of the few backing a packed 8KB region.
#define NCOPY   8
#define LSTRIDE 544                // u64 stride between lines (544*8 = 4352 B)

#define BETA_E_F 0.95122942450071400910f
#define BETA_I_F 0.90483741803595957316f
#define ALPHA_F  0.81873075307798185867f
#define RC_E_F   (100.0f * (1.0f - BETA_E_F))
#define RC_I_F   (100.0f * (1.0f - BETA_I_F))
#define U_REST_F  (-65.0f)
#define THETA_F   (-50.0f)
#define U_RESET_F (-65.0f)

typedef __attribute__((ext_vector_type(8))) short short8;
typedef __attribute__((ext_vector_type(4))) float f32x4;
typedef __attribute__((ext_vector_type(4))) int   i32x4;

// B-fragment-packed weights: [stripe 256][kb 144][lane 64][j 8] bf16
__device__ __attribute__((aligned(16))) uint16_t g_B[256 * KB_TOT * 512];
// tagged spike words, NCOPY-replicated, double-buffered by step parity.
// word wi (neurons 4wi..4wi+3, bit b of byte m = spike(batch b, neuron 4wi+m))
// lives at u64 offset (wi>>3)*LSTRIDE + (wi&7) of g_spk[copy][parity].
__device__ __attribute__((aligned(4096))) unsigned long long g_spk[NCOPY][2][128 * LSTRIDE];
__device__ __attribute__((aligned(16))) uint8_t g_inb[TSTEPS * N_IN]; // input bitmask bytes
__device__ float g_I[BATCH * N_NEUR];
__device__ float g_vr[BATCH * N_NEUR];

__device__ __forceinline__ uint16_t f2bf(float v) {
    uint32_t x = __float_as_uint(v);
    uint32_t r = x + 0x7FFFu + ((x >> 16) & 1u);
    return (uint16_t)(r >> 16);
}
__device__ __forceinline__ uint32_t bswz(uint32_t x) {  // middle-byte swap per 4-group
    return (x & 0xFF0000FFu) | ((x & 0x0000FF00u) << 8) | ((x >> 8) & 0x0000FF00u);
}

__global__ void prep_w(const float* __restrict__ W, const int* __restrict__ types) {
    int o = blockIdx.x * 256 + threadIdx.x;          // 2,097,152 threads
    int lane = o & 63, kb = (o >> 6) & 127, stripe = o >> 13;
    int col = (stripe << 4) + (lane & 15);
    float scale = (types[col] == 1) ? 0.5f : 2.0f;
    int kbase = kb * 32 + ((lane >> 4) & 3) * 8;
    uint32_t u[4];
#pragma unroll
    for (int p = 0; p < 4; ++p) {
        float v0 = W[(size_t)(kbase + 2 * p) * N_NEUR + col] * scale;
        float v1 = W[(size_t)(kbase + 2 * p + 1) * N_NEUR + col] * scale;
        u[p] = (uint32_t)f2bf(v0) | ((uint32_t)f2bf(v1) << 16);
    }
    i32x4 iv = { (int)u[0], (int)u[1], (int)u[2], (int)u[3] };
    ((short8*)g_B)[(stripe * KB_TOT + kb) * 64 + lane] = __builtin_bit_cast(short8, iv);
}

__global__ void prep_ff(const float* __restrict__ FF) {
    int o = blockIdx.x * 256 + threadIdx.x;          // 262,144 threads
    int lane = o & 63, kbl = (o >> 6) & 15, stripe = o >> 10;
    int col = (stripe << 4) + (lane & 15);
    int kbase = kbl * 32 + ((lane >> 4) & 3) * 8;
    uint32_t u[4];
#pragma unroll
    for (int p = 0; p < 4; ++p) {
        float v0 = FF[(size_t)(kbase + 2 * p) * N_NEUR + col];
        float v1 = FF[(size_t)(kbase + 2 * p + 1) * N_NEUR + col];
        u[p] = (uint32_t)f2bf(v0) | ((uint32_t)f2bf(v1) << 16);
    }
    i32x4 iv = { (int)u[0], (int)u[1], (int)u[2], (int)u[3] };
    ((short8*)g_B)[(stripe * KB_TOT + 128 + kbl) * 64 + lane] = __builtin_bit_cast(short8, iv);
}

__global__ void prep_in(const float* __restrict__ inp) {
    const int total = TSTEPS * N_IN;
    for (int o = blockIdx.x * 256 + threadIdx.x; o < total; o += gridDim.x * 256) {
        int t = o >> 9, i = o & 511;
        uint32_t m = 0;
#pragma unroll
        for (int b = 0; b < 8; ++b) {
            float v = inp[(size_t)(b * TSTEPS + t) * N_IN + i];
            m |= (v != 0.0f ? 1u : 0u) << b;
        }
        g_inb[o] = (uint8_t)m;
    }
}

__global__ void k_zero() {   // clear all tagged words in all replicas (replay safety)
    int i = blockIdx.x * 256 + threadIdx.x;          // 64 blocks -> 16384 words
    if (i < NCOPY * 2 * 1024) {
        int c = i >> 11;
        int p = (i >> 10) & 1;
        int wi = i & 1023;
        g_spk[c][p][(wi >> 3) * LSTRIDE + (wi & 7)] = 0ull;
    }
}

// step 0: v[1], s[1] from initial state; emits tau=0 outputs; seeds states + tagged words (tag=1)
__global__ void k_init(const float* __restrict__ v0p, const float* __restrict__ I0p,
                       const int* __restrict__ types, float* __restrict__ out) {
    __shared__ uint8_t sb[256];
    int n = blockIdx.x * 256 + threadIdx.x;
    bool exc = (types[n] == 1);
    float beta = exc ? BETA_E_F : BETA_I_F;
    float rc   = exc ? RC_E_F   : RC_I_F;
    uint32_t bits = 0;
#pragma unroll
    for (int b = 0; b < 8; ++b) {
        int gi = b * N_NEUR + n;
        float v0 = v0p[gi], I0 = I0p[gi];
        float v = U_REST_F + (v0 - U_REST_F) * beta + I0 * rc;
        bool s = (v >= THETA_F);
        float vr = s ? U_RESET_F : v;
        out[(size_t)(b * TSTEPS + 0) * N_NEUR + n] = s ? 1.0f : 0.0f;
        out[STRIDE_OUT + (size_t)(b * TSTEPS + 0) * N_NEUR + n] = vr;
        g_vr[gi] = vr;
        g_I[gi]  = I0;
        bits |= (s ? 1u : 0u) << b;
    }
    sb[threadIdx.x] = (uint8_t)bits;
    __syncthreads();
    if (threadIdx.x < 64) {
        int l = threadIdx.x * 4;
        uint32_t w = (uint32_t)sb[l] | ((uint32_t)sb[l + 1] << 8)
                   | ((uint32_t)sb[l + 2] << 16) | ((uint32_t)sb[l + 3] << 24);
        int wi = blockIdx.x * 64 + threadIdx.x;
        int off = (wi >> 3) * LSTRIDE + (wi & 7);
        unsigned long long tg = (1ull << 32) | (unsigned long long)w;
#pragma unroll
        for (int c = 0; c < NCOPY; ++c) g_spk[c][1][off] = tg;   // step-1 parity = 1
    }
}

// Persistent: 256 blocks (1/CU) x 512 threads; all 1000 steps in one dispatch.
// Sync = tagged u64 dataflow words, relaxed agent atomics, no fences, no RMW.
// Round-3 structure: per-wave decoupled poll->stage->MFMA (no block barrier
// before compute); s_sleep-throttled spin; dual acc chains; PLAIN output
// stores (nontemporal reverted: 64B-per-block chunks need LLC line merging).
__global__ void __launch_bounds__(512, 2)
k_persist(const int* __restrict__ types, float* __restrict__ out) {
    __shared__ __attribute__((aligned(16))) uint32_t swz[1152];
    __shared__ __attribute__((aligned(16))) float red[8][64][4];
    __shared__ unsigned long long wb[2];

    const int tid  = threadIdx.x;
    const int lane = tid & 63;
    const int w    = tid >> 6;
    const int blk  = blockIdx.x;
    const int stripe  = ((blk & 7) << 5) | (blk >> 3);
    const int colbase = stripe << 4;

    // ---- this wave's B slice into registers (resident all 1000 steps)
    short8 Breg[KB_PW];
    {
        const short8* Bp = (const short8*)g_B + ((size_t)stripe * KB_TOT + w * KB_PW) * 64 + lane;
#pragma unroll
        for (int i = 0; i < KB_PW; ++i) Breg[i] = Bp[i * 64];
    }

    // ---- epilogue-thread state in registers
    float Ireg = 0.f, vr = 0.f, beta = 0.f, rc = 0.f;
    int n = 0, b = 0;
    if (tid < 128) {
        b = tid >> 4;
        int nl = tid & 15;
        n = colbase + nl;
        int gi = b * N_NEUR + n;
        Ireg = g_I[gi];
        vr   = g_vr[gi];
        bool exc = (types[n] == 1);
        beta = exc ? BETA_E_F : BETA_I_F;
        rc   = exc ? RC_E_F   : RC_I_F;
    }

    const uint32_t msk = ((lane & 15) < 8) ? 0x00010001u : 0u;
    const int sA = lane & 7, sB = sA + 8;
    const int aoff = (lane >> 4) * 2;
    const int kb0 = w * KB_PW;

    // ---- per-wave poll slice: wave w consumes swz words [144w, 144w+144)
    const int base = w * KB_PW * 8;                  // = 144*w
    const int idx0 = base + 2 * lane;
    const int idx1 = idx0 + 1;
    const bool has2 = (lane < 16);
    const int idx2 = base + 128 + lane;              // valid only if has2
    const bool tg0 = (idx0 < 1024);                  // tagged (remote spike) words
    const bool tg1 = (idx1 < 1024);
    const bool tg2 = has2 && (idx2 < 1024);
    const int po0 = (idx0 >> 3) * LSTRIDE + (idx0 & 7);
    const int po1 = (idx1 >> 3) * LSTRIDE + (idx1 & 7);
    const int po2 = (idx2 >> 3) * LSTRIDE + (idx2 & 7);

    const unsigned long long* const sp0 = g_spk[blk & (NCOPY - 1)][0];
    const unsigned long long* const sp1 = g_spk[blk & (NCOPY - 1)][1];

    for (int t = 1; t <= TSTEPS; ++t) {
        // ---- input (untagged) words: issue immediately, overlap with poll
        const uint32_t* inw = (const uint32_t*)(g_inb + (size_t)(t - 1) * N_IN);
        uint32_t x0 = 0, x1 = 0, x2 = 0;
        if (!tg0) x0 = inw[idx0 - 1024];
        if (!tg1) x1 = inw[idx1 - 1024];
        if (has2 && !tg2) x2 = inw[idx2 - 1024];

        // ---- per-wave throttled-spin poll on this wave's tagged words
        {
            const unsigned long long* sp = (t & 1) ? sp1 : sp0;
            unsigned long long v0 = 0, v1 = 0, v2 = 0;
            bool d0 = !tg0, d1 = !tg1, d2 = !tg2;
            while (true) {
                if (!d0) { v0 = __hip_atomic_load(&sp[po0], __ATOMIC_RELAXED, __HIP_MEMORY_SCOPE_AGENT);
                           d0 = ((uint32_t)(v0 >> 32) == (uint32_t)t); }
                if (!d1) { v1 = __hip_atomic_load(&sp[po1], __ATOMIC_RELAXED, __HIP_MEMORY_SCOPE_AGENT);
                           d1 = ((uint32_t)(v1 >> 32) == (uint32_t)t); }
                if (!d2) { v2 = __hip_atomic_load(&sp[po2], __ATOMIC_RELAXED, __HIP_MEMORY_SCOPE_AGENT);
                           d2 = ((uint32_t)(v2 >> 32) == (uint32_t)t); }
                if (d0 && d1 && d2) break;
                __builtin_amdgcn_s_sleep(1);
            }
            if (tg0) x0 = (uint32_t)v0;
            if (tg1) x1 = (uint32_t)v1;
            if (tg2) x2 = (uint32_t)v2;
        }

        // ---- stage into this wave's private swz region (no block barrier needed)
        swz[idx0] = bswz(x0);
        swz[idx1] = bswz(x1);
        if (has2) swz[idx2] = bswz(x2);
        asm volatile("s_waitcnt lgkmcnt(0)" ::: "memory");
        __builtin_amdgcn_sched_barrier(0);

        // ---- MFMA over this wave's 18 k-blocks, B from registers, dual acc chains
        f32x4 acc0 = {0.f, 0.f, 0.f, 0.f};
        f32x4 acc1 = {0.f, 0.f, 0.f, 0.f};
#pragma unroll
        for (int it = 0; it < KB_PW; ++it) {
            int kb = kb0 + it;
            uint32_t w0 = swz[kb * 8 + aoff];
            uint32_t w1 = swz[kb * 8 + aoff + 1];
            uint32_t a0v = ((w0 >> sA) & msk) * 0x3F80u;
            uint32_t a1v = ((w0 >> sB) & msk) * 0x3F80u;
            uint32_t a2v = ((w1 >> sA) & msk) * 0x3F80u;
            uint32_t a3v = ((w1 >> sB) & msk) * 0x3F80u;
            i32x4 ai = { (int)a0v, (int)a1v, (int)a2v, (int)a3v };
            short8 av = __builtin_bit_cast(short8, ai);
            if (it & 1) acc1 = __builtin_amdgcn_mfma_f32_16x16x32_bf16(av, Breg[it], acc1, 0, 0, 0);
            else        acc0 = __builtin_amdgcn_mfma_f32_16x16x32_bf16(av, Breg[it], acc0, 0, 0, 0);
        }
        f32x4 acc = acc0 + acc1;
        *(f32x4*)&red[w][lane][0] = acc;
        __syncthreads();   // barrier A: all waves' red written

        // ---- epilogue: compute spikes FIRST (publish before output stores)
        float Inew = 0.f, vn = 0.f;
        bool sbit = false;
        if (tid < 128) {
            int nl = tid & 15;
            int rl = (b >> 2) * 16 + nl, rr = b & 3;
            float S = 0.f;
#pragma unroll
            for (int q = 0; q < 8; ++q) S += red[q][rl][rr];
            Inew = Ireg * ALPHA_F + S;
            Ireg = Inew;
            if (t < TSTEPS) {
                float v = U_REST_F + (vr - U_REST_F) * beta + Inew * rc;
                sbit = (v >= THETA_F);
                vn = sbit ? U_RESET_F : v;
                vr = vn;
            }
            unsigned long long bal = __ballot(sbit);  // wave0: b0..3, wave1: b4..7
            if ((tid & 63) == 0) wb[tid >> 6] = bal;
        }
        __syncthreads();   // barrier B: wb visible; red consumed (safe to rewrite next iter)

        // ---- publish s[t+1] as tagged words to ALL replicas, THEN issue output stores
        if (t < TSTEPS && tid < 4 * NCOPY) {
            unsigned long long b0 = wb[0], b1 = wb[1];
            const int j = tid & 3, c = tid >> 2;        // lane -> (word j, replica c)
            uint32_t word = 0;
#pragma unroll
            for (int u = 0; u < 4; ++u) {
                int nn = j * 4 + u;
                uint32_t byte = 0;
#pragma unroll
                for (int q = 0; q < 4; ++q) {
                    byte |= (uint32_t)((b0 >> (nn + 16 * q)) & 1ull) << q;
                    byte |= (uint32_t)((b1 >> (nn + 16 * q)) & 1ull) << (q + 4);
                }
                word |= byte << (8 * u);
            }
            unsigned long long tg = ((unsigned long long)(t + 1) << 32) | (unsigned long long)word;
            const int wi = stripe * 4 + j;
            __hip_atomic_store(&g_spk[c][(t + 1) & 1][(wi >> 3) * LSTRIDE + (wi & 7)], tg,
                               __ATOMIC_RELAXED, __HIP_MEMORY_SCOPE_AGENT);
        }
        if (tid < 128) {
            out[2 * STRIDE_OUT + (size_t)(b * TSTEPS + (t - 1)) * N_NEUR + n] = Inew;
            if (t < TSTEPS) {
                out[(size_t)(b * TSTEPS + t) * N_NEUR + n] = sbit ? 1.0f : 0.0f;
                out[STRIDE_OUT + (size_t)(b * TSTEPS + t) * N_NEUR + n] = vn;
            }
        }
    }
}

extern "C" void kernel_launch(void* const* d_in, const int* in_sizes, int n_in,
                              void* d_out, int out_size, void* d_ws, size_t ws_size,
                              hipStream_t stream) {
    const int*   types = (const int*)d_in[0];
    const float* Wrec  = (const float*)d_in[1];
    const float* FF    = (const float*)d_in[2];
    const float* inp   = (const float*)d_in[3];
    const float* v0    = (const float*)d_in[4];
    const float* I0    = (const float*)d_in[5];
    float* out = (float*)d_out;
    (void)in_sizes; (void)n_in; (void)out_size; (void)d_ws; (void)ws_size;

    hipLaunchKernelGGL(prep_w,  dim3(8192), dim3(256), 0, stream, Wrec, types);
    hipLaunchKernelGGL(prep_ff, dim3(1024), dim3(256), 0, stream, FF);
    hipLaunchKernelGGL(prep_in, dim3(512),  dim3(256), 0, stream, inp);
    hipLaunchKernelGGL(k_zero,  dim3(64),   dim3(256), 0, stream);
    hipLaunchKernelGGL(k_init,  dim3(16),   dim3(256), 0, stream, v0, I0, types, out);
    hipLaunchKernelGGL(k_persist, dim3(256), dim3(512), 0, stream, types, out);
}

// Round 6
// 4221.229 us; speedup vs baseline: 1.0064x; 1.0064x over previous
//
#include <hip/hip_runtime.h>
#include <stdint.h>

#define N_NEUR 4096
#define N_IN   512
#define BATCH  8
#define TSTEPS 1000
#define KB_REC 128                 // 128 k-blocks of 32 for recurrent W
#define KB_TOT 144                 // + 16 k-blocks for feedforward (K = 4608)
#define KB_PW  18                  // k-blocks per wave (144 / 8 waves)
#define STRIDE_OUT (BATCH * TSTEPS * N_NEUR)

// Spike-exchange layout: NCOPY replicas (readers per line 256 -> 32) and a
// 4352-byte (17*256) stride between 64B lines so the hot set spreads across
// ~all LLC channels instead of the few backing a packed 8KB region.
#define NCOPY   8
#define LSTRIDE 544                // u64 stride between lines (544*8 = 4352 B)

#define BETA_E_F 0.95122942450071400910f
#define BETA_I_F 0.90483741803595957316f
#define ALPHA_F  0.81873075307798185867f
#define RC_E_F   (100.0f * (1.0f - BETA_E_F))
#define RC_I_F   (100.0f * (1.0f - BETA_I_F))
#define U_REST_F  (-65.0f)
#define THETA_F   (-50.0f)
#define U_RESET_F (-65.0f)

typedef __attribute__((ext_vector_type(8))) short short8;
typedef __attribute__((ext_vector_type(4))) float f32x4;
typedef __attribute__((ext_vector_type(4))) int   i32x4;

// B-fragment-packed weights: [stripe 256][kb 144][lane 64][j 8] bf16
__device__ __attribute__((aligned(16))) uint16_t g_B[256 * KB_TOT * 512];
// tagged spike words, NCOPY-replicated, double-buffered by step parity.
// word wi (neurons 4wi..4wi+3, bit b of byte m = spike(batch b, neuron 4wi+m))
// lives at u64 offset (wi>>3)*LSTRIDE + (wi&7) of g_spk[copy][parity].
__device__ __attribute__((aligned(4096))) unsigned long long g_spk[NCOPY][2][128 * LSTRIDE];
__device__ __attribute__((aligned(16))) uint8_t g_inb[TSTEPS * N_IN]; // input bitmask bytes
__device__ float g_I[BATCH * N_NEUR];
__device__ float g_vr[BATCH * N_NEUR];

__device__ __forceinline__ uint16_t f2bf(float v) {
    uint32_t x = __float_as_uint(v);
    uint32_t r = x + 0x7FFFu + ((x >> 16) & 1u);
    return (uint16_t)(r >> 16);
}
__device__ __forceinline__ uint32_t bswz(uint32_t x) {  // middle-byte swap per 4-group
    return (x & 0xFF0000FFu) | ((x & 0x0000FF00u) << 8) | ((x >> 8) & 0x0000FF00u);
}

__global__ void prep_w(const float* __restrict__ W, const int* __restrict__ types) {
    int o = blockIdx.x * 256 + threadIdx.x;          // 2,097,152 threads
    int lane = o & 63, kb = (o >> 6) & 127, stripe = o >> 13;
    int col = (stripe << 4) + (lane & 15);
    float scale = (types[col] == 1) ? 0.5f : 2.0f;
    int kbase = kb * 32 + ((lane >> 4) & 3) * 8;
    uint32_t u[4];
#pragma unroll
    for (int p = 0; p < 4; ++p) {
        float v0 = W[(size_t)(kbase + 2 * p) * N_NEUR + col] * scale;
        float v1 = W[(size_t)(kbase + 2 * p + 1) * N_NEUR + col] * scale;
        u[p] = (uint32_t)f2bf(v0) | ((uint32_t)f2bf(v1) << 16);
    }
    i32x4 iv = { (int)u[0], (int)u[1], (int)u[2], (int)u[3] };
    ((short8*)g_B)[(stripe * KB_TOT + kb) * 64 + lane] = __builtin_bit_cast(short8, iv);
}

__global__ void prep_ff(const float* __restrict__ FF) {
    int o = blockIdx.x * 256 + threadIdx.x;          // 262,144 threads
    int lane = o & 63, kbl = (o >> 6) & 15, stripe = o >> 10;
    int col = (stripe << 4) + (lane & 15);
    int kbase = kbl * 32 + ((lane >> 4) & 3) * 8;
    uint32_t u[4];
#pragma unroll
    for (int p = 0; p < 4; ++p) {
        float v0 = FF[(size_t)(kbase + 2 * p) * N_NEUR + col];
        float v1 = FF[(size_t)(kbase + 2 * p + 1) * N_NEUR + col];
        u[p] = (uint32_t)f2bf(v0) | ((uint32_t)f2bf(v1) << 16);
    }
    i32x4 iv = { (int)u[0], (int)u[1], (int)u[2], (int)u[3] };
    ((short8*)g_B)[(stripe * KB_TOT + 128 + kbl) * 64 + lane] = __builtin_bit_cast(short8, iv);
}

__global__ void prep_in(const float* __restrict__ inp) {
    const int total = TSTEPS * N_IN;
    for (int o = blockIdx.x * 256 + threadIdx.x; o < total; o += gridDim.x * 256) {
        int t = o >> 9, i = o & 511;
        uint32_t m = 0;
#pragma unroll
        for (int b = 0; b < 8; ++b) {
            float v = inp[(size_t)(b * TSTEPS + t) * N_IN + i];
            m |= (v != 0.0f ? 1u : 0u) << b;
        }
        g_inb[o] = (uint8_t)m;
    }
}

__global__ void k_zero() {   // clear all tagged words in all replicas (replay safety)
    int i = blockIdx.x * 256 + threadIdx.x;          // 64 blocks -> 16384 words
    if (i < NCOPY * 2 * 1024) {
        int c = i >> 11;
        int p = (i >> 10) & 1;
        int wi = i & 1023;
        g_spk[c][p][(wi >> 3) * LSTRIDE + (wi & 7)] = 0ull;
    }
}

// step 0: v[1], s[1] from initial state; emits tau=0 outputs; seeds states + tagged words (tag=1)
__global__ void k_init(const float* __restrict__ v0p, const float* __restrict__ I0p,
                       const int* __restrict__ types, float* __restrict__ out) {
    __shared__ uint8_t sb[256];
    int n = blockIdx.x * 256 + threadIdx.x;
    bool exc = (types[n] == 1);
    float beta = exc ? BETA_E_F : BETA_I_F;
    float rc   = exc ? RC_E_F   : RC_I_F;
    uint32_t bits = 0;
#pragma unroll
    for (int b = 0; b < 8; ++b) {
        int gi = b * N_NEUR + n;
        float v0 = v0p[gi], I0 = I0p[gi];
        float v = U_REST_F + (v0 - U_REST_F) * beta + I0 * rc;
        bool s = (v >= THETA_F);
        float vr = s ? U_RESET_F : v;
        out[(size_t)(b * TSTEPS + 0) * N_NEUR + n] = s ? 1.0f : 0.0f;
        out[STRIDE_OUT + (size_t)(b * TSTEPS + 0) * N_NEUR + n] = vr;
        g_vr[gi] = vr;
        g_I[gi]  = I0;
        bits |= (s ? 1u : 0u) << b;
    }
    sb[threadIdx.x] = (uint8_t)bits;
    __syncthreads();
    if (threadIdx.x < 64) {
        int l = threadIdx.x * 4;
        uint32_t w = (uint32_t)sb[l] | ((uint32_t)sb[l + 1] << 8)
                   | ((uint32_t)sb[l + 2] << 16) | ((uint32_t)sb[l + 3] << 24);
        int wi = blockIdx.x * 64 + threadIdx.x;
        int off = (wi >> 3) * LSTRIDE + (wi & 7);
        unsigned long long tg = (1ull << 32) | (unsigned long long)w;
#pragma unroll
        for (int c = 0; c < NCOPY; ++c) g_spk[c][1][off] = tg;   // step-1 parity = 1
    }
}

// Persistent: 256 blocks (1/CU) x 512 threads; all 1000 steps in one dispatch.
// Sync = tagged u64 dataflow words, relaxed agent atomics, no fences, no RMW.
// Round-6 = round-1 structure + (a) wave-local publish: epilogue remapped so
// each wave's ballot holds its own 2 spike words -> publish right after the
// ballot, barrier B deleted (red WAR is covered by next iter's stage barrier);
// (b) 3 independent MFMA accumulator chains (shorter dependent-latency chain).
__global__ void __launch_bounds__(512, 2)
k_persist(const int* __restrict__ types, float* __restrict__ out) {
    __shared__ __attribute__((aligned(16))) uint32_t swz[1152];
    __shared__ __attribute__((aligned(16))) float red[8][64][4];

    const int tid  = threadIdx.x;
    const int lane = tid & 63;
    const int w    = tid >> 6;
    const int blk  = blockIdx.x;
    const int stripe  = ((blk & 7) << 5) | (blk >> 3);
    const int colbase = stripe << 4;

    // ---- this wave's B slice into registers (resident all 1000 steps)
    short8 Breg[KB_PW];
    {
        const short8* Bp = (const short8*)g_B + ((size_t)stripe * KB_TOT + w * KB_PW) * 64 + lane;
#pragma unroll
        for (int i = 0; i < KB_PW; ++i) Breg[i] = Bp[i * 64];
    }

    // ---- epilogue-thread state in registers
    // NEW mapping (wave-local publish): wave 0 = cols 0..7, wave 1 = cols 8..15;
    // within a wave: b = lane>>3, local col = lane&7. Ballot bit(lane) = s(b, col).
    float Ireg = 0.f, vr = 0.f, beta = 0.f, rc = 0.f;
    int n = 0, b = 0, c16 = 0;
    if (tid < 128) {
        b   = lane >> 3;
        c16 = (tid >> 6) * 8 + (lane & 7);
        n   = colbase + c16;
        int gi = b * N_NEUR + n;
        Ireg = g_I[gi];
        vr   = g_vr[gi];
        bool exc = (types[n] == 1);
        beta = exc ? BETA_E_F : BETA_I_F;
        rc   = exc ? RC_E_F   : RC_I_F;
    }

    const uint32_t msk = ((lane & 15) < 8) ? 0x00010001u : 0u;
    const int sA = lane & 7, sB = sA + 8;
    const int aoff = (lane >> 4) * 2;
    const int kb0 = w * KB_PW;

    // this block's replica + precomputed spread addresses for its two poll words
    const unsigned long long* const sp0 = g_spk[blk & (NCOPY - 1)][0];
    const unsigned long long* const sp1 = g_spk[blk & (NCOPY - 1)][1];
    const int a0 = ((tid >> 3) * LSTRIDE) | (tid & 7);            // word tid
    const int a1 = (((tid + 512) >> 3) * LSTRIDE) | (tid & 7);    // word tid+512

    for (int t = 1; t <= TSTEPS; ++t) {
        // ---- stage: distributed poll on tagged words (2 per thread), then swizzle into LDS
        {
            const unsigned long long* sp = (t & 1) ? sp1 : sp0;
            unsigned long long v0 = 0, v1 = 0;
            bool d0 = false, d1 = false;
            while (true) {
                if (!d0) { v0 = __hip_atomic_load(&sp[a0], __ATOMIC_RELAXED, __HIP_MEMORY_SCOPE_AGENT);
                           d0 = ((uint32_t)(v0 >> 32) == (uint32_t)t); }
                if (!d1) { v1 = __hip_atomic_load(&sp[a1], __ATOMIC_RELAXED, __HIP_MEMORY_SCOPE_AGENT);
                           d1 = ((uint32_t)(v1 >> 32) == (uint32_t)t); }
                if (d0 && d1) break;
                __builtin_amdgcn_s_sleep(1);
            }
            swz[tid] = bswz((uint32_t)v0);
            swz[tid + 512] = bswz((uint32_t)v1);
            if (tid < 128) {
                uint32_t x = ((const uint32_t*)(g_inb + (size_t)(t - 1) * N_IN))[tid];
                swz[1024 + tid] = bswz(x);
            }
        }
        __syncthreads();   // stage barrier: swz ready; also red WAR vs prev-iter readers

        // ---- MFMA over this wave's 18 k-blocks, B from registers, 3 indep chains
        f32x4 acc0 = {0.f, 0.f, 0.f, 0.f};
        f32x4 acc1 = {0.f, 0.f, 0.f, 0.f};
        f32x4 acc2 = {0.f, 0.f, 0.f, 0.f};
#pragma unroll
        for (int it = 0; it < KB_PW; ++it) {
            int kb = kb0 + it;
            uint32_t w0 = swz[kb * 8 + aoff];
            uint32_t w1 = swz[kb * 8 + aoff + 1];
            uint32_t a0v = ((w0 >> sA) & msk) * 0x3F80u;
            uint32_t a1v = ((w0 >> sB) & msk) * 0x3F80u;
            uint32_t a2v = ((w1 >> sA) & msk) * 0x3F80u;
            uint32_t a3v = ((w1 >> sB) & msk) * 0x3F80u;
            i32x4 ai = { (int)a0v, (int)a1v, (int)a2v, (int)a3v };
            short8 av = __builtin_bit_cast(short8, ai);
            int ch = it - (it / 3) * 3;   // it % 3, compile-time per unrolled iter
            if (ch == 0)      acc0 = __builtin_amdgcn_mfma_f32_16x16x32_bf16(av, Breg[it], acc0, 0, 0, 0);
            else if (ch == 1) acc1 = __builtin_amdgcn_mfma_f32_16x16x32_bf16(av, Breg[it], acc1, 0, 0, 0);
            else              acc2 = __builtin_amdgcn_mfma_f32_16x16x32_bf16(av, Breg[it], acc2, 0, 0, 0);
        }
        f32x4 acc = (acc0 + acc1) + acc2;
        *(f32x4*)&red[w][lane][0] = acc;
        __syncthreads();   // barrier A: all waves' red written

        // ---- epilogue: spikes -> wave-local ballot -> IMMEDIATE publish -> out stores
        if (tid < 128) {
            float Inew, vn = 0.f;
            bool sbit = false;
            const int rl = ((b >> 2) << 4) + c16, rr = b & 3;
            float S = 0.f;
#pragma unroll
            for (int q = 0; q < 8; ++q) S += red[q][rl][rr];
            Inew = Ireg * ALPHA_F + S;
            Ireg = Inew;
            if (t < TSTEPS) {
                float v = U_REST_F + (vr - U_REST_F) * beta + Inew * rc;
                sbit = (v >= THETA_F);
                vn = sbit ? U_RESET_F : v;
                vr = vn;
            }
            // ballot bit(lane) = s(b = lane>>3, local col = lane&7) for this wave's 8 cols
            unsigned long long bal = __ballot(sbit);
            // wave-local publish: lanes 0..15 -> (word j2 = lane&1, replica c = lane>>1)
            if (t < TSTEPS && lane < 16) {
                const int j2 = lane & 1, c = lane >> 1;
                uint32_t word = 0;
#pragma unroll
                for (int m = 0; m < 4; ++m) {
                    // byte m = batch bits of local col (4*j2 + m): gather bit (8b + cl) over b
                    unsigned long long tt = (bal >> (4 * j2 + m)) & 0x0101010101010101ull;
                    uint32_t byte = (uint32_t)((tt * 0x0102040810204080ull) >> 56);
                    word |= byte << (8 * m);
                }
                unsigned long long tg = ((unsigned long long)(t + 1) << 32) | (unsigned long long)word;
                const int wi = stripe * 4 + (tid >> 6) * 2 + j2;
                __hip_atomic_store(&g_spk[c][(t + 1) & 1][(wi >> 3) * LSTRIDE + (wi & 7)], tg,
                                   __ATOMIC_RELAXED, __HIP_MEMORY_SCOPE_AGENT);
            }
            // output stores AFTER publish (publish is the global critical path)
            out[2 * STRIDE_OUT + (size_t)(b * TSTEPS + (t - 1)) * N_NEUR + n] = Inew;
            if (t < TSTEPS) {
                out[(size_t)(b * TSTEPS + t) * N_NEUR + n] = sbit ? 1.0f : 0.0f;
                out[STRIDE_OUT + (size_t)(b * TSTEPS + t) * N_NEUR + n] = vn;
            }
        }
    }
}

extern "C" void kernel_launch(void* const* d_in, const int* in_sizes, int n_in,
                              void* d_out, int out_size, void* d_ws, size_t ws_size,
                              hipStream_t stream) {
    const int*   types = (const int*)d_in[0];
    const float* Wrec  = (const float*)d_in[1];
    const float* FF    = (const float*)d_in[2];
    const float* inp   = (const float*)d_in[3];
    const float* v0    = (const float*)d_in[4];
    const float* I0    = (const float*)d_in[5];
    float* out = (float*)d_out;
    (void)in_sizes; (void)n_in; (void)out_size; (void)d_ws; (void)ws_size;

    hipLaunchKernelGGL(prep_w,  dim3(8192), dim3(256), 0, stream, Wrec, types);
    hipLaunchKernelGGL(prep_ff, dim3(1024), dim3(256), 0, stream, FF);
    hipLaunchKernelGGL(prep_in, dim3(512),  dim3(256), 0, stream, inp);
    hipLaunchKernelGGL(k_zero,  dim3(64),   dim3(256), 0, stream);
    hipLaunchKernelGGL(k_init,  dim3(16),   dim3(256), 0, stream, v0, I0, types, out);
    hipLaunchKernelGGL(k_persist, dim3(256), dim3(512), 0, stream, types, out);
}

// Round 7
// 4021.345 us; speedup vs baseline: 1.0564x; 1.0497x over previous
//
#include <hip/hip_runtime.h>
#include <stdint.h>

#define N_NEUR 4096
#define N_IN   512
#define BATCH  8
#define TSTEPS 1000
#define KB_REC 128                 // 128 k-blocks of 32 for recurrent W
#define KB_TOT 144                 // + 16 k-blocks for feedforward (K = 4608)
#define KB_PW  18                  // k-blocks per wave (144 / 8 waves)
#define STRIDE_OUT (BATCH * TSTEPS * N_NEUR)

// Spike-exchange layout: NCOPY replicas (readers per line 256/NCOPY = 16) and a
// 4352-byte (17*256) stride between 64B lines so the hot set spreads across
// ~all LLC channels instead of the few backing a packed 8KB region.
#define NCOPY   16
#define LSTRIDE 544                // u64 stride between lines (544*8 = 4352 B)

#define BETA_E_F 0.95122942450071400910f
#define BETA_I_F 0.90483741803595957316f
#define ALPHA_F  0.81873075307798185867f
#define RC_E_F   (100.0f * (1.0f - BETA_E_F))
#define RC_I_F   (100.0f * (1.0f - BETA_I_F))
#define U_REST_F  (-65.0f)
#define THETA_F   (-50.0f)
#define U_RESET_F (-65.0f)

typedef __attribute__((ext_vector_type(8))) short short8;
typedef __attribute__((ext_vector_type(4))) float f32x4;
typedef __attribute__((ext_vector_type(4))) int   i32x4;

// B-fragment-packed weights: [stripe 256][kb 144][lane 64][j 8] bf16
__device__ __attribute__((aligned(16))) uint16_t g_B[256 * KB_TOT * 512];
// tagged spike words, NCOPY-replicated, double-buffered by step parity.
// word wi (neurons 4wi..4wi+3, bit b of byte m = spike(batch b, neuron 4wi+m))
// lives at u64 offset (wi>>3)*LSTRIDE + (wi&7) of g_spk[copy][parity].
__device__ __attribute__((aligned(4096))) unsigned long long g_spk[NCOPY][2][128 * LSTRIDE];
__device__ __attribute__((aligned(16))) uint8_t g_inb[TSTEPS * N_IN]; // input bitmask bytes
__device__ float g_I[BATCH * N_NEUR];
__device__ float g_vr[BATCH * N_NEUR];

__device__ __forceinline__ uint16_t f2bf(float v) {
    uint32_t x = __float_as_uint(v);
    uint32_t r = x + 0x7FFFu + ((x >> 16) & 1u);
    return (uint16_t)(r >> 16);
}
__device__ __forceinline__ uint32_t bswz(uint32_t x) {  // middle-byte swap per 4-group
    return (x & 0xFF0000FFu) | ((x & 0x0000FF00u) << 8) | ((x >> 8) & 0x0000FF00u);
}

__global__ void prep_w(const float* __restrict__ W, const int* __restrict__ types) {
    int o = blockIdx.x * 256 + threadIdx.x;          // 2,097,152 threads
    int lane = o & 63, kb = (o >> 6) & 127, stripe = o >> 13;
    int col = (stripe << 4) + (lane & 15);
    float scale = (types[col] == 1) ? 0.5f : 2.0f;
    int kbase = kb * 32 + ((lane >> 4) & 3) * 8;
    uint32_t u[4];
#pragma unroll
    for (int p = 0; p < 4; ++p) {
        float v0 = W[(size_t)(kbase + 2 * p) * N_NEUR + col] * scale;
        float v1 = W[(size_t)(kbase + 2 * p + 1) * N_NEUR + col] * scale;
        u[p] = (uint32_t)f2bf(v0) | ((uint32_t)f2bf(v1) << 16);
    }
    i32x4 iv = { (int)u[0], (int)u[1], (int)u[2], (int)u[3] };
    ((short8*)g_B)[(stripe * KB_TOT + kb) * 64 + lane] = __builtin_bit_cast(short8, iv);
}

__global__ void prep_ff(const float* __restrict__ FF) {
    int o = blockIdx.x * 256 + threadIdx.x;          // 262,144 threads
    int lane = o & 63, kbl = (o >> 6) & 15, stripe = o >> 10;
    int col = (stripe << 4) + (lane & 15);
    int kbase = kbl * 32 + ((lane >> 4) & 3) * 8;
    uint32_t u[4];
#pragma unroll
    for (int p = 0; p < 4; ++p) {
        float v0 = FF[(size_t)(kbase + 2 * p) * N_NEUR + col];
        float v1 = FF[(size_t)(kbase + 2 * p + 1) * N_NEUR + col];
        u[p] = (uint32_t)f2bf(v0) | ((uint32_t)f2bf(v1) << 16);
    }
    i32x4 iv = { (int)u[0], (int)u[1], (int)u[2], (int)u[3] };
    ((short8*)g_B)[(stripe * KB_TOT + 128 + kbl) * 64 + lane] = __builtin_bit_cast(short8, iv);
}

__global__ void prep_in(const float* __restrict__ inp) {
    const int total = TSTEPS * N_IN;
    for (int o = blockIdx.x * 256 + threadIdx.x; o < total; o += gridDim.x * 256) {
        int t = o >> 9, i = o & 511;
        uint32_t m = 0;
#pragma unroll
        for (int b = 0; b < 8; ++b) {
            float v = inp[(size_t)(b * TSTEPS + t) * N_IN + i];
            m |= (v != 0.0f ? 1u : 0u) << b;
        }
        g_inb[o] = (uint8_t)m;
    }
}

__global__ void k_zero() {   // clear all tagged words in all replicas (replay safety)
    int i = blockIdx.x * 256 + threadIdx.x;          // 128 blocks -> 32768 words
    if (i < NCOPY * 2 * 1024) {
        int c = i >> 11;
        int p = (i >> 10) & 1;
        int wi = i & 1023;
        g_spk[c][p][(wi >> 3) * LSTRIDE + (wi & 7)] = 0ull;
    }
}

// step 0: v[1], s[1] from initial state; emits tau=0 outputs; seeds states + tagged words (tag=1)
__global__ void k_init(const float* __restrict__ v0p, const float* __restrict__ I0p,
                       const int* __restrict__ types, float* __restrict__ out) {
    __shared__ uint8_t sb[256];
    int n = blockIdx.x * 256 + threadIdx.x;
    bool exc = (types[n] == 1);
    float beta = exc ? BETA_E_F : BETA_I_F;
    float rc   = exc ? RC_E_F   : RC_I_F;
    uint32_t bits = 0;
#pragma unroll
    for (int b = 0; b < 8; ++b) {
        int gi = b * N_NEUR + n;
        float v0 = v0p[gi], I0 = I0p[gi];
        float v = U_REST_F + (v0 - U_REST_F) * beta + I0 * rc;
        bool s = (v >= THETA_F);
        float vr = s ? U_RESET_F : v;
        out[(size_t)(b * TSTEPS + 0) * N_NEUR + n] = s ? 1.0f : 0.0f;
        out[STRIDE_OUT + (size_t)(b * TSTEPS + 0) * N_NEUR + n] = vr;
        g_vr[gi] = vr;
        g_I[gi]  = I0;
        bits |= (s ? 1u : 0u) << b;
    }
    sb[threadIdx.x] = (uint8_t)bits;
    __syncthreads();
    if (threadIdx.x < 64) {
        int l = threadIdx.x * 4;
        uint32_t w = (uint32_t)sb[l] | ((uint32_t)sb[l + 1] << 8)
                   | ((uint32_t)sb[l + 2] << 16) | ((uint32_t)sb[l + 3] << 24);
        int wi = blockIdx.x * 64 + threadIdx.x;
        int off = (wi >> 3) * LSTRIDE + (wi & 7);
        unsigned long long tg = (1ull << 32) | (unsigned long long)w;
#pragma unroll
        for (int c = 0; c < NCOPY; ++c) g_spk[c][1][off] = tg;   // step-1 parity = 1
    }
}

// Persistent: 256 blocks (1/CU) x 512 threads; all 1000 steps in one dispatch.
// Sync = tagged u64 dataflow words, relaxed agent atomics, no fences, no RMW.
// Round-7 = EXACT round-1 structure (best measured: 3490 us) with ONE change:
// NCOPY 8 -> 16 (readers per spike line 32 -> 16). Everything else identical.
__global__ void __launch_bounds__(512, 2)
k_persist(const int* __restrict__ types, float* __restrict__ out) {
    __shared__ __attribute__((aligned(16))) uint32_t swz[1152];
    __shared__ __attribute__((aligned(16))) float red[8][64][4];
    __shared__ unsigned long long wb[2];

    const int tid  = threadIdx.x;
    const int lane = tid & 63;
    const int w    = tid >> 6;
    const int blk  = blockIdx.x;
    const int stripe  = ((blk & 7) << 5) | (blk >> 3);
    const int colbase = stripe << 4;

    // ---- this wave's B slice into registers (resident all 1000 steps)
    short8 Breg[KB_PW];
    {
        const short8* Bp = (const short8*)g_B + ((size_t)stripe * KB_TOT + w * KB_PW) * 64 + lane;
#pragma unroll
        for (int i = 0; i < KB_PW; ++i) Breg[i] = Bp[i * 64];
    }

    // ---- epilogue-thread state in registers
    float Ireg = 0.f, vr = 0.f, beta = 0.f, rc = 0.f;
    int n = 0, b = 0;
    if (tid < 128) {
        b = tid >> 4;
        int nl = tid & 15;
        n = colbase + nl;
        int gi = b * N_NEUR + n;
        Ireg = g_I[gi];
        vr   = g_vr[gi];
        bool exc = (types[n] == 1);
        beta = exc ? BETA_E_F : BETA_I_F;
        rc   = exc ? RC_E_F   : RC_I_F;
    }

    const uint32_t msk = ((lane & 15) < 8) ? 0x00010001u : 0u;
    const int sA = lane & 7, sB = sA + 8;
    const int aoff = (lane >> 4) * 2;
    const int kb0 = w * KB_PW;

    // this block's replica + precomputed spread addresses for its two poll words
    const unsigned long long* const sp0 = g_spk[blk & (NCOPY - 1)][0];
    const unsigned long long* const sp1 = g_spk[blk & (NCOPY - 1)][1];
    const int a0 = ((tid >> 3) * LSTRIDE) | (tid & 7);            // word tid
    const int a1 = (((tid + 512) >> 3) * LSTRIDE) | (tid & 7);    // word tid+512

    for (int t = 1; t <= TSTEPS; ++t) {
        // ---- stage: distributed poll on tagged words (2 per thread), then swizzle into LDS
        {
            const unsigned long long* sp = (t & 1) ? sp1 : sp0;
            unsigned long long v0 = 0, v1 = 0;
            bool d0 = false, d1 = false;
            while (true) {
                if (!d0) { v0 = __hip_atomic_load(&sp[a0], __ATOMIC_RELAXED, __HIP_MEMORY_SCOPE_AGENT);
                           d0 = ((uint32_t)(v0 >> 32) == (uint32_t)t); }
                if (!d1) { v1 = __hip_atomic_load(&sp[a1], __ATOMIC_RELAXED, __HIP_MEMORY_SCOPE_AGENT);
                           d1 = ((uint32_t)(v1 >> 32) == (uint32_t)t); }
                if (d0 && d1) break;
                __builtin_amdgcn_s_sleep(1);
            }
            swz[tid] = bswz((uint32_t)v0);
            swz[tid + 512] = bswz((uint32_t)v1);
            if (tid < 128) {
                uint32_t x = ((const uint32_t*)(g_inb + (size_t)(t - 1) * N_IN))[tid];
                swz[1024 + tid] = bswz(x);
            }
        }
        __syncthreads();   // also drains prev-iter output stores (overlapped with poll)

        // ---- MFMA over this wave's 18 k-blocks, B from registers
        f32x4 acc = {0.f, 0.f, 0.f, 0.f};
#pragma unroll
        for (int it = 0; it < KB_PW; ++it) {
            int kb = kb0 + it;
            uint32_t w0 = swz[kb * 8 + aoff];
            uint32_t w1 = swz[kb * 8 + aoff + 1];
            uint32_t a0v = ((w0 >> sA) & msk) * 0x3F80u;
            uint32_t a1v = ((w0 >> sB) & msk) * 0x3F80u;
            uint32_t a2v = ((w1 >> sA) & msk) * 0x3F80u;
            uint32_t a3v = ((w1 >> sB) & msk) * 0x3F80u;
            i32x4 ai = { (int)a0v, (int)a1v, (int)a2v, (int)a3v };
            short8 av = __builtin_bit_cast(short8, ai);
            acc = __builtin_amdgcn_mfma_f32_16x16x32_bf16(av, Breg[it], acc, 0, 0, 0);
        }
        *(f32x4*)&red[w][lane][0] = acc;
        __syncthreads();

        // ---- epilogue: compute spikes FIRST (publish before output stores)
        float Inew = 0.f, vn = 0.f;
        bool sbit = false;
        if (tid < 128) {
            int nl = tid & 15;
            int rl = (b >> 2) * 16 + nl, rr = b & 3;
            float S = 0.f;
#pragma unroll
            for (int q = 0; q < 8; ++q) S += red[q][rl][rr];
            Inew = Ireg * ALPHA_F + S;
            Ireg = Inew;
            if (t < TSTEPS) {
                float v = U_REST_F + (vr - U_REST_F) * beta + Inew * rc;
                sbit = (v >= THETA_F);
                vn = sbit ? U_RESET_F : v;
                vr = vn;
            }
            unsigned long long bal = __ballot(sbit);  // wave0: b0..3, wave1: b4..7
            if ((tid & 63) == 0) wb[tid >> 6] = bal;
        }
        __syncthreads();   // cheap: no global ops pending since last barrier

        // ---- publish s[t+1] as tagged words to ALL replicas, THEN issue output stores
        if (t < TSTEPS && tid < 4 * NCOPY) {
            unsigned long long b0 = wb[0], b1 = wb[1];
            const int j = tid & 3, c = tid >> 2;        // lane -> (word j, replica c)
            uint32_t word = 0;
#pragma unroll
            for (int u = 0; u < 4; ++u) {
                int nn = j * 4 + u;
                uint32_t byte = 0;
#pragma unroll
                for (int q = 0; q < 4; ++q) {
                    byte |= (uint32_t)((b0 >> (nn + 16 * q)) & 1ull) << q;
                    byte |= (uint32_t)((b1 >> (nn + 16 * q)) & 1ull) << (q + 4);
                }
                word |= byte << (8 * u);
            }
            unsigned long long tg = ((unsigned long long)(t + 1) << 32) | (unsigned long long)word;
            const int wi = stripe * 4 + j;
            __hip_atomic_store(&g_spk[c][(t + 1) & 1][(wi >> 3) * LSTRIDE + (wi & 7)], tg,
                               __ATOMIC_RELAXED, __HIP_MEMORY_SCOPE_AGENT);
        }
        if (tid < 128) {
            out[2 * STRIDE_OUT + (size_t)(b * TSTEPS + (t - 1)) * N_NEUR + n] = Inew;
            if (t < TSTEPS) {
                out[(size_t)(b * TSTEPS + t) * N_NEUR + n] = sbit ? 1.0f : 0.0f;
                out[STRIDE_OUT + (size_t)(b * TSTEPS + t) * N_NEUR + n] = vn;
            }
        }
    }
}

extern "C" void kernel_launch(void* const* d_in, const int* in_sizes, int n_in,
                              void* d_out, int out_size, void* d_ws, size_t ws_size,
                              hipStream_t stream) {
    const int*   types = (const int*)d_in[0];
    const float* Wrec  = (const float*)d_in[1];
    const float* FF    = (const float*)d_in[2];
    const float* inp   = (const float*)d_in[3];
    const float* v0    = (const float*)d_in[4];
    const float* I0    = (const float*)d_in[5];
    float* out = (float*)d_out;
    (void)in_sizes; (void)n_in; (void)out_size; (void)d_ws; (void)ws_size;

    hipLaunchKernelGGL(prep_w,  dim3(8192), dim3(256), 0, stream, Wrec, types);
    hipLaunchKernelGGL(prep_ff, dim3(1024), dim3(256), 0, stream, FF);
    hipLaunchKernelGGL(prep_in, dim3(512),  dim3(256), 0, stream, inp);
    hipLaunchKernelGGL(k_zero,  dim3(128),  dim3(256), 0, stream);
    hipLaunchKernelGGL(k_init,  dim3(16),   dim3(256), 0, stream, v0, I0, types, out);
    hipLaunchKernelGGL(k_persist, dim3(256), dim3(512), 0, stream, types, out);
}

// Round 8
// 3673.496 us; speedup vs baseline: 1.1565x; 1.0947x over previous
//
#include <hip/hip_runtime.h>
#include <stdint.h>

#define N_NEUR 4096
#define N_IN   512
#define BATCH  8
#define TSTEPS 1000
#define KB_REC 128                 // 128 k-blocks of 32 for recurrent W
#define KB_TOT 144                 // + 16 k-blocks for feedforward (K = 4608)
#define KB_PW  18                  // k-blocks per wave (144 / 8 waves)
#define STRIDE_OUT (BATCH * TSTEPS * N_NEUR)

// Spike-exchange layout: NCOPY replicas (readers per line 256 -> 32) and a
// 4352-byte (17*256) stride between 64B lines so the hot set spreads across
// ~all LLC channels instead of the few backing a packed 8KB region.
// R7 measured NCOPY=16 as a net loss -> 8 is the optimum of this family.
#define NCOPY   8
#define LSTRIDE 544                // u64 stride between lines (544*8 = 4352 B)

#define BETA_E_F 0.95122942450071400910f
#define BETA_I_F 0.90483741803595957316f
#define ALPHA_F  0.81873075307798185867f
#define RC_E_F   (100.0f * (1.0f - BETA_E_F))
#define RC_I_F   (100.0f * (1.0f - BETA_I_F))
#define U_REST_F  (-65.0f)
#define THETA_F   (-50.0f)
#define U_RESET_F (-65.0f)

typedef __attribute__((ext_vector_type(8))) short short8;
typedef __attribute__((ext_vector_type(4))) float f32x4;
typedef __attribute__((ext_vector_type(4))) int   i32x4;

// B-fragment-packed weights: [stripe 256][kb 144][lane 64][j 8] bf16
__device__ __attribute__((aligned(16))) uint16_t g_B[256 * KB_TOT * 512];
// tagged spike words, NCOPY-replicated, double-buffered by step parity.
// word wi (neurons 4wi..4wi+3, bit b of byte m = spike(batch b, neuron 4wi+m))
// lives at u64 offset (wi>>3)*LSTRIDE + (wi&7) of g_spk[copy][parity].
__device__ __attribute__((aligned(4096))) unsigned long long g_spk[NCOPY][2][128 * LSTRIDE];
__device__ __attribute__((aligned(16))) uint8_t g_inb[TSTEPS * N_IN]; // input bitmask bytes
__device__ float g_I[BATCH * N_NEUR];
__device__ float g_vr[BATCH * N_NEUR];

__device__ __forceinline__ uint16_t f2bf(float v) {
    uint32_t x = __float_as_uint(v);
    uint32_t r = x + 0x7FFFu + ((x >> 16) & 1u);
    return (uint16_t)(r >> 16);
}
__device__ __forceinline__ uint32_t bswz(uint32_t x) {  // middle-byte swap per 4-group
    return (x & 0xFF0000FFu) | ((x & 0x0000FF00u) << 8) | ((x >> 8) & 0x0000FF00u);
}

__global__ void prep_w(const float* __restrict__ W, const int* __restrict__ types) {
    int o = blockIdx.x * 256 + threadIdx.x;          // 2,097,152 threads
    int lane = o & 63, kb = (o >> 6) & 127, stripe = o >> 13;
    int col = (stripe << 4) + (lane & 15);
    float scale = (types[col] == 1) ? 0.5f : 2.0f;
    int kbase = kb * 32 + ((lane >> 4) & 3) * 8;
    uint32_t u[4];
#pragma unroll
    for (int p = 0; p < 4; ++p) {
        float v0 = W[(size_t)(kbase + 2 * p) * N_NEUR + col] * scale;
        float v1 = W[(size_t)(kbase + 2 * p + 1) * N_NEUR + col] * scale;
        u[p] = (uint32_t)f2bf(v0) | ((uint32_t)f2bf(v1) << 16);
    }
    i32x4 iv = { (int)u[0], (int)u[1], (int)u[2], (int)u[3] };
    ((short8*)g_B)[(stripe * KB_TOT + kb) * 64 + lane] = __builtin_bit_cast(short8, iv);
}

__global__ void prep_ff(const float* __restrict__ FF) {
    int o = blockIdx.x * 256 + threadIdx.x;          // 262,144 threads
    int lane = o & 63, kbl = (o >> 6) & 15, stripe = o >> 10;
    int col = (stripe << 4) + (lane & 15);
    int kbase = kbl * 32 + ((lane >> 4) & 3) * 8;
    uint32_t u[4];
#pragma unroll
    for (int p = 0; p < 4; ++p) {
        float v0 = FF[(size_t)(kbase + 2 * p) * N_NEUR + col];
        float v1 = FF[(size_t)(kbase + 2 * p + 1) * N_NEUR + col];
        u[p] = (uint32_t)f2bf(v0) | ((uint32_t)f2bf(v1) << 16);
    }
    i32x4 iv = { (int)u[0], (int)u[1], (int)u[2], (int)u[3] };
    ((short8*)g_B)[(stripe * KB_TOT + 128 + kbl) * 64 + lane] = __builtin_bit_cast(short8, iv);
}

__global__ void prep_in(const float* __restrict__ inp) {
    const int total = TSTEPS * N_IN;
    for (int o = blockIdx.x * 256 + threadIdx.x; o < total; o += gridDim.x * 256) {
        int t = o >> 9, i = o & 511;
        uint32_t m = 0;
#pragma unroll
        for (int b = 0; b < 8; ++b) {
            float v = inp[(size_t)(b * TSTEPS + t) * N_IN + i];
            m |= (v != 0.0f ? 1u : 0u) << b;
        }
        g_inb[o] = (uint8_t)m;
    }
}

__global__ void k_zero() {   // clear all tagged words in all replicas (replay safety)
    int i = blockIdx.x * 256 + threadIdx.x;          // 64 blocks -> 16384 words
    if (i < NCOPY * 2 * 1024) {
        int c = i >> 11;
        int p = (i >> 10) & 1;
        int wi = i & 1023;
        g_spk[c][p][(wi >> 3) * LSTRIDE + (wi & 7)] = 0ull;
    }
}

// step 0: v[1], s[1] from initial state; emits tau=0 outputs; seeds states + tagged words (tag=1)
__global__ void k_init(const float* __restrict__ v0p, const float* __restrict__ I0p,
                       const int* __restrict__ types, float* __restrict__ out) {
    __shared__ uint8_t sb[256];
    int n = blockIdx.x * 256 + threadIdx.x;
    bool exc = (types[n] == 1);
    float beta = exc ? BETA_E_F : BETA_I_F;
    float rc   = exc ? RC_E_F   : RC_I_F;
    uint32_t bits = 0;
#pragma unroll
    for (int b = 0; b < 8; ++b) {
        int gi = b * N_NEUR + n;
        float v0 = v0p[gi], I0 = I0p[gi];
        float v = U_REST_F + (v0 - U_REST_F) * beta + I0 * rc;
        bool s = (v >= THETA_F);
        float vr = s ? U_RESET_F : v;
        out[(size_t)(b * TSTEPS + 0) * N_NEUR + n] = s ? 1.0f : 0.0f;
        out[STRIDE_OUT + (size_t)(b * TSTEPS + 0) * N_NEUR + n] = vr;
        g_vr[gi] = vr;
        g_I[gi]  = I0;
        bits |= (s ? 1u : 0u) << b;
    }
    sb[threadIdx.x] = (uint8_t)bits;
    __syncthreads();
    if (threadIdx.x < 64) {
        int l = threadIdx.x * 4;
        uint32_t w = (uint32_t)sb[l] | ((uint32_t)sb[l + 1] << 8)
                   | ((uint32_t)sb[l + 2] << 16) | ((uint32_t)sb[l + 3] << 24);
        int wi = blockIdx.x * 64 + threadIdx.x;
        int off = (wi >> 3) * LSTRIDE + (wi & 7);
        unsigned long long tg = (1ull << 32) | (unsigned long long)w;
#pragma unroll
        for (int c = 0; c < NCOPY; ++c) g_spk[c][1][off] = tg;   // step-1 parity = 1
    }
}

// Persistent: 256 blocks (1/CU) x 512 threads; all 1000 steps in one dispatch.
// Sync = tagged u64 dataflow words, relaxed agent atomics, no fences, no RMW.
// Round-8 = EXACT round-1 structure (best measured: 3490 us) with ONE isolated
// change: 18-deep dependent MFMA chain split into 3 independent chains of 6
// (shortens the serial dependent-latency path between the two barriers).
__global__ void __launch_bounds__(512, 2)
k_persist(const int* __restrict__ types, float* __restrict__ out) {
    __shared__ __attribute__((aligned(16))) uint32_t swz[1152];
    __shared__ __attribute__((aligned(16))) float red[8][64][4];
    __shared__ unsigned long long wb[2];

    const int tid  = threadIdx.x;
    const int lane = tid & 63;
    const int w    = tid >> 6;
    const int blk  = blockIdx.x;
    const int stripe  = ((blk & 7) << 5) | (blk >> 3);
    const int colbase = stripe << 4;

    // ---- this wave's B slice into registers (resident all 1000 steps)
    short8 Breg[KB_PW];
    {
        const short8* Bp = (const short8*)g_B + ((size_t)stripe * KB_TOT + w * KB_PW) * 64 + lane;
#pragma unroll
        for (int i = 0; i < KB_PW; ++i) Breg[i] = Bp[i * 64];
    }

    // ---- epilogue-thread state in registers
    float Ireg = 0.f, vr = 0.f, beta = 0.f, rc = 0.f;
    int n = 0, b = 0;
    if (tid < 128) {
        b = tid >> 4;
        int nl = tid & 15;
        n = colbase + nl;
        int gi = b * N_NEUR + n;
        Ireg = g_I[gi];
        vr   = g_vr[gi];
        bool exc = (types[n] == 1);
        beta = exc ? BETA_E_F : BETA_I_F;
        rc   = exc ? RC_E_F   : RC_I_F;
    }

    const uint32_t msk = ((lane & 15) < 8) ? 0x00010001u : 0u;
    const int sA = lane & 7, sB = sA + 8;
    const int aoff = (lane >> 4) * 2;
    const int kb0 = w * KB_PW;

    // this block's replica + precomputed spread addresses for its two poll words
    const unsigned long long* const sp0 = g_spk[blk & (NCOPY - 1)][0];
    const unsigned long long* const sp1 = g_spk[blk & (NCOPY - 1)][1];
    const int a0 = ((tid >> 3) * LSTRIDE) | (tid & 7);            // word tid
    const int a1 = (((tid + 512) >> 3) * LSTRIDE) | (tid & 7);    // word tid+512

    for (int t = 1; t <= TSTEPS; ++t) {
        // ---- stage: distributed poll on tagged words (2 per thread), then swizzle into LDS
        {
            const unsigned long long* sp = (t & 1) ? sp1 : sp0;
            unsigned long long v0 = 0, v1 = 0;
            bool d0 = false, d1 = false;
            while (true) {
                if (!d0) { v0 = __hip_atomic_load(&sp[a0], __ATOMIC_RELAXED, __HIP_MEMORY_SCOPE_AGENT);
                           d0 = ((uint32_t)(v0 >> 32) == (uint32_t)t); }
                if (!d1) { v1 = __hip_atomic_load(&sp[a1], __ATOMIC_RELAXED, __HIP_MEMORY_SCOPE_AGENT);
                           d1 = ((uint32_t)(v1 >> 32) == (uint32_t)t); }
                if (d0 && d1) break;
                __builtin_amdgcn_s_sleep(1);
            }
            swz[tid] = bswz((uint32_t)v0);
            swz[tid + 512] = bswz((uint32_t)v1);
            if (tid < 128) {
                uint32_t x = ((const uint32_t*)(g_inb + (size_t)(t - 1) * N_IN))[tid];
                swz[1024 + tid] = bswz(x);
            }
        }
        __syncthreads();   // also drains prev-iter output stores (overlapped with poll)

        // ---- MFMA over this wave's 18 k-blocks, B from registers, 3 indep chains
        f32x4 acc0 = {0.f, 0.f, 0.f, 0.f};
        f32x4 acc1 = {0.f, 0.f, 0.f, 0.f};
        f32x4 acc2 = {0.f, 0.f, 0.f, 0.f};
#pragma unroll
        for (int it = 0; it < KB_PW; ++it) {
            int kb = kb0 + it;
            uint32_t w0 = swz[kb * 8 + aoff];
            uint32_t w1 = swz[kb * 8 + aoff + 1];
            uint32_t a0v = ((w0 >> sA) & msk) * 0x3F80u;
            uint32_t a1v = ((w0 >> sB) & msk) * 0x3F80u;
            uint32_t a2v = ((w1 >> sA) & msk) * 0x3F80u;
            uint32_t a3v = ((w1 >> sB) & msk) * 0x3F80u;
            i32x4 ai = { (int)a0v, (int)a1v, (int)a2v, (int)a3v };
            short8 av = __builtin_bit_cast(short8, ai);
            int ch = it - (it / 3) * 3;   // it % 3, compile-time constant per unrolled iter
            if (ch == 0)      acc0 = __builtin_amdgcn_mfma_f32_16x16x32_bf16(av, Breg[it], acc0, 0, 0, 0);
            else if (ch == 1) acc1 = __builtin_amdgcn_mfma_f32_16x16x32_bf16(av, Breg[it], acc1, 0, 0, 0);
            else              acc2 = __builtin_amdgcn_mfma_f32_16x16x32_bf16(av, Breg[it], acc2, 0, 0, 0);
        }
        f32x4 acc = (acc0 + acc1) + acc2;
        *(f32x4*)&red[w][lane][0] = acc;
        __syncthreads();

        // ---- epilogue: compute spikes FIRST (publish before output stores)
        float Inew = 0.f, vn = 0.f;
        bool sbit = false;
        if (tid < 128) {
            int nl = tid & 15;
            int rl = (b >> 2) * 16 + nl, rr = b & 3;
            float S = 0.f;
#pragma unroll
            for (int q = 0; q < 8; ++q) S += red[q][rl][rr];
            Inew = Ireg * ALPHA_F + S;
            Ireg = Inew;
            if (t < TSTEPS) {
                float v = U_REST_F + (vr - U_REST_F) * beta + Inew * rc;
                sbit = (v >= THETA_F);
                vn = sbit ? U_RESET_F : v;
                vr = vn;
            }
            unsigned long long bal = __ballot(sbit);  // wave0: b0..3, wave1: b4..7
            if ((tid & 63) == 0) wb[tid >> 6] = bal;
        }
        __syncthreads();   // cheap: no global ops pending since last barrier

        // ---- publish s[t+1] as tagged words, THEN issue output stores
        if (t < TSTEPS && tid < 4 * NCOPY) {
            unsigned long long b0 = wb[0], b1 = wb[1];
            const int j = tid & 3, c = tid >> 2;        // lane -> (word j, replica c)
            uint32_t word = 0;
#pragma unroll
            for (int u = 0; u < 4; ++u) {
                int nn = j * 4 + u;
                uint32_t byte = 0;
#pragma unroll
                for (int q = 0; q < 4; ++q) {
                    byte |= (uint32_t)((b0 >> (nn + 16 * q)) & 1ull) << q;
                    byte |= (uint32_t)((b1 >> (nn + 16 * q)) & 1ull) << (q + 4);
                }
                word |= byte << (8 * u);
            }
            unsigned long long tg = ((unsigned long long)(t + 1) << 32) | (unsigned long long)word;
            const int wi = stripe * 4 + j;
            __hip_atomic_store(&g_spk[c][(t + 1) & 1][(wi >> 3) * LSTRIDE + (wi & 7)], tg,
                               __ATOMIC_RELAXED, __HIP_MEMORY_SCOPE_AGENT);
        }
        if (tid < 128) {
            out[2 * STRIDE_OUT + (size_t)(b * TSTEPS + (t - 1)) * N_NEUR + n] = Inew;
            if (t < TSTEPS) {
                out[(size_t)(b * TSTEPS + t) * N_NEUR + n] = sbit ? 1.0f : 0.0f;
                out[STRIDE_OUT + (size_t)(b * TSTEPS + t) * N_NEUR + n] = vn;
            }
        }
    }
}

extern "C" void kernel_launch(void* const* d_in, const int* in_sizes, int n_in,
                              void* d_out, int out_size, void* d_ws, size_t ws_size,
                              hipStream_t stream) {
    const int*   types = (const int*)d_in[0];
    const float* Wrec  = (const float*)d_in[1];
    const float* FF    = (const float*)d_in[2];
    const float* inp   = (const float*)d_in[3];
    const float* v0    = (const float*)d_in[4];
    const float* I0    = (const float*)d_in[5];
    float* out = (float*)d_out;
    (void)in_sizes; (void)n_in; (void)out_size; (void)d_ws; (void)ws_size;

    hipLaunchKernelGGL(prep_w,  dim3(8192), dim3(256), 0, stream, Wrec, types);
    hipLaunchKernelGGL(prep_ff, dim3(1024), dim3(256), 0, stream, FF);
    hipLaunchKernelGGL(prep_in, dim3(512),  dim3(256), 0, stream, inp);
    hipLaunchKernelGGL(k_zero,  dim3(64),   dim3(256), 0, stream);
    hipLaunchKernelGGL(k_init,  dim3(16),   dim3(256), 0, stream, v0, I0, types, out);
    hipLaunchKernelGGL(k_persist, dim3(256), dim3(512), 0, stream, types, out);
}